// Round 10
// baseline (312.616 us; speedup 1.0000x reference)
//
#include <hip/hip_runtime.h>
#include <stdint.h>

#define S_LEN 2048
#define D_DIM 128

typedef __attribute__((ext_vector_type(8)))  short bf16x8;
typedef __attribute__((ext_vector_type(4)))  short bf16x4;
typedef __attribute__((ext_vector_type(4)))  float f32x4;
typedef __attribute__((ext_vector_type(2)))  float f32x2;
typedef __attribute__((ext_vector_type(16))) float f32x16;

__device__ __forceinline__ short f2bf(float f) {
  union { float f; uint32_t u; } c; c.f = f;
  uint32_t u = c.u;
  u += 0x7fffu + ((u >> 16) & 1u);
  return (short)(u >> 16);
}
__device__ __forceinline__ uint32_t pk2bf(float a, float b) {
#if __has_builtin(__builtin_amdgcn_cvt_pk_bf16_f32)
  typedef __attribute__((ext_vector_type(2))) __bf16 bf2;
  union { bf2 v; uint32_t u; } cv;
  cv.v = __builtin_amdgcn_cvt_pk_bf16_f32(a, b);
  return cv.u;
#else
  return (uint32_t)(uint16_t)f2bf(a) | (((uint32_t)(uint16_t)f2bf(b)) << 16);
#endif
}
__device__ __forceinline__ float fexp2(float x) {
#if __has_builtin(__builtin_amdgcn_exp2f)
  return __builtin_amdgcn_exp2f(x);   // raw v_exp_f32, no ocml guard code
#else
  return exp2f(x);
#endif
}
__device__ __forceinline__ bf16x8 mk8(uint32_t a, uint32_t b, uint32_t c, uint32_t d) {
  union { uint32_t u[4]; bf16x8 v; } x;
  x.u[0] = a; x.u[1] = b; x.u[2] = c; x.u[3] = d;
  return x.v;
}
__device__ __forceinline__ void gl_lds16(const short* g, short* l) {
  __builtin_amdgcn_global_load_lds((const __attribute__((address_space(1))) void*)g,
                                   (__attribute__((address_space(3))) void*)l, 16, 0, 0);
}

// ---------------- preprocess ----------------
// blocks [0,512): V -> Vt bf16, transposed to [bh][d][key], keys bit-swapped
// (b2<->b3 per 16-group) to match attn_main's in-register P permutation.
// blocks [512,2560): K fp32->bf16 linear.
__global__ __launch_bounds__(256) void pre_kernel(
    const float* __restrict__ K, const float* __restrict__ V,
    short* __restrict__ Kb, short* __restrict__ Vt) {
  const int t = threadIdx.x;
  if (blockIdx.x >= 512) {
    int i0 = (blockIdx.x - 512) * 256 + t;
#pragma unroll
    for (int r = 0; r < 4; ++r) {
      int i = i0 + r * 524288;
      f32x4 v = ((const f32x4*)K)[i];
      *(uint2*)(Kb + (size_t)i * 4) = make_uint2(pk2bf(v[0], v[1]), pk2bf(v[2], v[3]));
    }
    return;
  }
  __shared__ __align__(16) uint32_t sU[128][64];  // [d][swizzled k2]
  const int vb = blockIdx.x;
  const int bh = vb >> 4;
  const int k0 = (vb & 15) * 128;
  const float* src = V + ((size_t)bh * S_LEN + k0) * D_DIM;
  {
    // phase 1: load key-row pairs coalesced, pack along k, conflict-free b32 writes
    const int a = t & 31;               // d4 = 4a
    const int E = 2 * (a & 15);
    const float* s0 = src + (size_t)(t >> 5) * 2 * D_DIM + a * 4;
#pragma unroll
    for (int p = 0; p < 8; ++p) {
      f32x4 vA = *(const f32x4*)(s0 + p * 16 * D_DIM);
      f32x4 vB = *(const f32x4*)(s0 + p * 16 * D_DIM + D_DIM);
      const int k2 = p * 8 + (t >> 5);  // u32 index = key pair (2k2, 2k2+1)
      const int col = k2 ^ E;
#pragma unroll
      for (int j = 0; j < 4; ++j)
        sU[4 * a + j][col] = pk2bf(vA[j], vB[j]);
    }
  }
  __syncthreads();
  {
    // phase 2: per thread one d-row; 8 x 16B stores; 2 x ds_read_b64 each.
    const int d = t >> 1;
    const int E = 2 * ((t >> 3) & 15);  // 2*((d>>2)&15)
    short* out = Vt + ((size_t)bh * D_DIM + d) * S_LEN + k0 + (t & 1) * 8;
#pragma unroll
    for (int g = 0; g < 8; ++g) {
      const int pb = g * 16 + (t & 1) * 8;
      const int kb1 = ((pb >> 4) << 4) + ((pb & 15) ? 4 : 0);  // bit2<->bit3 swap
      const int k2a = kb1 >> 1;         // even
      const int k2b = k2a + 4;          // kb2 = kb1 + 8
      uint2 lo = *(const uint2*)&sU[d][k2a ^ E];
      uint2 hi = *(const uint2*)&sU[d][k2b ^ E];
      uint4 o; o.x = lo.x; o.y = lo.y; o.z = hi.x; o.w = hi.y;
      *(uint4*)(out + g * 16) = o;
    }
  }
}

// ---------------- main kernel ----------------
// DECOUPLED-WAVE structure. WG 256 / 4 waves = (qp: q-half of 32, dh:
// d-half of 64). Each wave computes QK^T for ALL 64 keys of the chunk
// (two 32x32 S^T tiles, 16 MFMA) and PV for ONLY its own 64-d half
// (4 ksteps x 2 dtiles, 8 MFMA). P stays in-register per wave: NO sP
// exchange, NO sLinv, ONE barrier per chunk. Row-sums are wave-local
// (shfl_xor(32)); sRed[64] written by dh=0 wave at c==3, read by both
// dh waves after the next barrier (loadLv). QK+softmax are duplicated
// across the dh pair -- the price for removing all cross-wave coupling.
// Accumulators stay oa[2]/oj[2]/ojb[2] (register-safe; rounds 4-6 proved
// oa[4]-style doubling spills). All acc indices compile-time (rule #20).
__global__ __launch_bounds__(256, 2) void attn_main(
    const short* __restrict__ Kb, const short* __restrict__ Vt,
    const float* __restrict__ Q, float* __restrict__ O) {
  __shared__ __align__(16) short ring[2][16384];  // per slot: K 16KB | V 16KB
  __shared__ float sRed[64];                      // [64 q] block row-sums
  // total LDS = 65536 + 256 = 65792 B -> 2 blocks/CU

  const int t = threadIdx.x;
  const int w = t >> 6;
  const int lane = t & 63;
  const int l31 = lane & 31;
  const int hi = lane >> 5;
  const int dh = w & 1;                 // d-half ownership (was key-half h)
  const int qp = w >> 1;

  // XCD swizzle: bh = (b&7)*4 + ((b>>3)&3), qtile = b>>5
  const int b = blockIdx.x;
  const int bh = (b & 7) * 4 + ((b >> 3) & 3);
  const int q0 = (b >> 5) * 64;

  const short* Kh = Kb + (size_t)bh * S_LEN * D_DIM;
  const short* Vh = Vt + (size_t)bh * D_DIM * S_LEN;

  // staging constants (K rows: 16 granules, mask 15; V rows: 8 granules, mask 7)
  const int kKey = t >> 4;                       // + r*16
  const int kG   = (t & 15) ^ (kKey & 15);
  const int vD   = t >> 3;                       // + r*32
  const int vG   = (t & 7) ^ (vD & 7);

  auto stageK = [&](int key0, int slot) {
    const short* src = Kh + (size_t)(key0 + kKey) * D_DIM + kG * 8;
    short* dst = &ring[slot][t * 8];
#pragma unroll
    for (int r = 0; r < 4; ++r) gl_lds16(src + r * 16 * D_DIM, dst + r * 2048);
  };
  auto stageV = [&](int key0, int slot) {
    const short* src = Vh + (size_t)vD * S_LEN + key0 + vG * 8;
    short* dst = &ring[slot][8192 + t * 8];
#pragma unroll
    for (int r = 0; r < 4; ++r) gl_lds16(src + (size_t)r * 32 * S_LEN, dst + r * 2048);
  };

  // ---- Q fragments: load fp32, scale, pack (register-resident) ----
  bf16x8 qf[8];
  {
    const float QSCALE = 0.12751743f;  // 128^-0.5 * log2(e)
    const float* Qg = Q + ((size_t)bh * S_LEN + q0 + qp * 32 + l31) * D_DIM;
#pragma unroll
    for (int ks = 0; ks < 8; ++ks) {
      f32x4 a = *(const f32x4*)(Qg + ks * 16 + hi * 8);
      f32x4 c = *(const f32x4*)(Qg + ks * 16 + hi * 8 + 4);
      qf[ks] = mk8(pk2bf(a[0] * QSCALE, a[1] * QSCALE), pk2bf(a[2] * QSCALE, a[3] * QSCALE),
                   pk2bf(c[0] * QSCALE, c[1] * QSCALE), pk2bf(c[2] * QSCALE, c[3] * QSCALE));
    }
  }

  // K A-frag LDS offsets (shorts): tile0 row = l31 (keys 0-31 of chunk),
  // tile1 = +32 rows (= +4096 shorts; same granule XOR since mask 15).
  int aK[8];
#pragma unroll
  for (int ks = 0; ks < 8; ++ks)
    aK[ks] = l31 * 128 + (((2 * ks + hi) ^ (l31 & 15)) << 3);
  // V B-frag offsets: row d = dh*64 (+dt*32 via +2048 shorts) + l31,
  // kstep u granule (u*2+hi), XOR on l31&7
  int aV[4];
#pragma unroll
  for (int u = 0; u < 4; ++u)
    aV[u] = (dh * 64 + l31) * 64 + (((u * 2 + hi) ^ (l31 & 7)) << 3);

  f32x16 oa[2], oj[2], ojb[2];
#pragma unroll
  for (int d = 0; d < 2; ++d)
#pragma unroll
    for (int r = 0; r < 16; ++r) { oa[d][r] = 0.f; oj[d][r] = 0.f; ojb[d][r] = 0.f; }

  float ssum = 0.f;

  // lv from sRed (full row-sums, written by dh=0 wave last block)
  auto loadLv = [&](f32x4* lv) {
#pragma unroll
    for (int g = 0; g < 4; ++g) {
      f32x4 s = *(const f32x4*)&sRed[qp * 32 + g * 8 + 4 * hi];
      lv[g][0] = __fdividef(1.0f, s[0]);
      lv[g][1] = __fdividef(1.0f, s[1]);
      lv[g][2] = __fdividef(1.0f, s[2]);
      lv[g][3] = __fdividef(1.0f, s[3]);
    }
  };

  stageK(0, 0); stageV(0, 0);

  for (int j = 0; j < 8; ++j) {
#pragma unroll
    for (int c = 0; c < 4; ++c) {
      const int G = j * 4 + c;
      const int slot = G & 1;
      __syncthreads();  // chunk G staged; ring[slot^1] consumed; sRed visible
      if (G + 1 < 32) { stageK((G + 1) * 64, slot ^ 1); stageV((G + 1) * 64, slot ^ 1); }

      if (c == 0 && j > 0) {
        // normalize previous block: oa += (oj + ojb) * linv (then clear)
        f32x4 lv[4];
        loadLv(lv);
#pragma unroll
        for (int d = 0; d < 2; ++d)
#pragma unroll
          for (int r = 0; r < 16; ++r) {
            oa[d][r] += (oj[d][r] + ojb[d][r]) * lv[r >> 2][r & 3];
            oj[d][r] = 0.f;
            ojb[d][r] = 0.f;
          }
      }

      // ---- QK^T: BOTH 32x32 tiles (all 64 keys), 2 independent chains ----
      const short* pK = &ring[slot][0];
      f32x16 sc0, sc1;
#pragma unroll
      for (int r = 0; r < 16; ++r) { sc0[r] = 0.f; sc1[r] = 0.f; }
#pragma unroll
      for (int ks = 0; ks < 8; ++ks) {
        bf16x8 a0 = *(const bf16x8*)(pK + aK[ks]);
        bf16x8 a1 = *(const bf16x8*)(pK + aK[ks] + 4096);
        sc0 = __builtin_amdgcn_mfma_f32_32x32x16_bf16(a0, qf[ks], sc0, 0, 0, 0);
        sc1 = __builtin_amdgcn_mfma_f32_32x32x16_bf16(a1, qf[ks], sc1, 0, 0, 0);
      }
#pragma unroll
      for (int r = 0; r < 16; ++r) { sc0[r] = fexp2(sc0[r]); sc1[r] = fexp2(sc1[r]); }

      // pack UNNORMALIZED P to A-frags (key perm matched by Vt pre-swap):
      // pf[0..1] from tile0 (keys 0-31), pf[2..3] from tile1 (keys 32-63)
      bf16x8 pf[4];
#pragma unroll
      for (int t2 = 0; t2 < 2; ++t2) {
        pf[t2] = mk8(pk2bf(sc0[8 * t2 + 0], sc0[8 * t2 + 1]), pk2bf(sc0[8 * t2 + 2], sc0[8 * t2 + 3]),
                     pk2bf(sc0[8 * t2 + 4], sc0[8 * t2 + 5]), pk2bf(sc0[8 * t2 + 6], sc0[8 * t2 + 7]));
        pf[2 + t2] = mk8(pk2bf(sc1[8 * t2 + 0], sc1[8 * t2 + 1]), pk2bf(sc1[8 * t2 + 2], sc1[8 * t2 + 3]),
                         pk2bf(sc1[8 * t2 + 4], sc1[8 * t2 + 5]), pk2bf(sc1[8 * t2 + 6], sc1[8 * t2 + 7]));
      }
      {  // tree-sum both tiles (depth 5)
        float a0 = sc0[0] + sc0[1], a1 = sc0[2] + sc0[3], a2 = sc0[4] + sc0[5], a3 = sc0[6] + sc0[7];
        float a4 = sc0[8] + sc0[9], a5 = sc0[10] + sc0[11], a6 = sc0[12] + sc0[13], a7 = sc0[14] + sc0[15];
        float b0 = sc1[0] + sc1[1], b1 = sc1[2] + sc1[3], b2 = sc1[4] + sc1[5], b3 = sc1[6] + sc1[7];
        float b4 = sc1[8] + sc1[9], b5 = sc1[10] + sc1[11], b6 = sc1[12] + sc1[13], b7 = sc1[14] + sc1[15];
        float c0 = (a0 + a1) + (a2 + a3), c1 = (a4 + a5) + (a6 + a7);
        float c2 = (b0 + b1) + (b2 + b3), c3 = (b4 + b5) + (b6 + b7);
        ssum += (c0 + c1) + (c2 + c3);
      }
      if (c == 3) {
        ssum += __shfl_xor(ssum, 32);
        if (dh == 0 && lane < 32) sRed[qp * 32 + l31] = ssum;
        ssum = 0.f;
      }

      // ---- PV: own d-half only; 4 ksteps (u) x 2 dtiles; u<2->oj, else ojb ----
      const short* pV = &ring[slot][8192];
#pragma unroll
      for (int u = 0; u < 4; ++u) {
        bf16x8 a = pf[u];
#pragma unroll
        for (int dt = 0; dt < 2; ++dt) {
          bf16x8 bv = *(const bf16x8*)(pV + aV[u] + dt * 2048);
          if (u < 2)
            oj[dt] = __builtin_amdgcn_mfma_f32_32x32x16_bf16(a, bv, oj[dt], 0, 0, 0);
          else
            ojb[dt] = __builtin_amdgcn_mfma_f32_32x32x16_bf16(a, bv, ojb[dt], 0, 0, 0);
        }
      }
    }
  }

  __syncthreads();  // sRed (last block) visible
  // final normalize + store (wave fully owns its (qp, dh) output tile)
  {
    f32x4 lv[4];
    loadLv(lv);
    float* Og = O + ((size_t)bh * S_LEN + q0) * D_DIM;
#pragma unroll
    for (int d = 0; d < 2; ++d)
#pragma unroll
      for (int r = 0; r < 16; ++r) {
        float val = oa[d][r] + (oj[d][r] + ojb[d][r]) * lv[r >> 2][r & 3];
        int row = qp * 32 + (r & 3) + 8 * (r >> 2) + 4 * hi;
        int col = dh * 64 + d * 32 + l31;
        Og[row * D_DIM + col] = val;
      }
  }
}

extern "C" void kernel_launch(void* const* d_in, const int* in_sizes, int n_in,
                              void* d_out, int out_size, void* d_ws, size_t ws_size,
                              hipStream_t stream) {
  const float* Q = (const float*)d_in[0];
  const float* K = (const float*)d_in[1];
  const float* V = (const float*)d_in[2];
  float* Out = (float*)d_out;
  const size_t tElems = (size_t)32 * S_LEN * D_DIM;

  short* Kb  = (short*)d_ws;
  short* Vtb = Kb + tElems;

  pre_kernel<<<2560, 256, 0, stream>>>(K, V, Kb, Vtb);
  attn_main<<<1024, 256, 0, stream>>>(Kb, Vtb, Q, Out);
}

// Round 11
// 273.891 us; speedup vs baseline: 1.1414x; 1.1414x over previous
//
#include <hip/hip_runtime.h>
#include <stdint.h>

#define S_LEN 2048
#define D_DIM 128

typedef __attribute__((ext_vector_type(8)))  short bf16x8;
typedef __attribute__((ext_vector_type(4)))  short bf16x4;
typedef __attribute__((ext_vector_type(4)))  float f32x4;
typedef __attribute__((ext_vector_type(2)))  float f32x2;
typedef __attribute__((ext_vector_type(16))) float f32x16;

__device__ __forceinline__ short f2bf(float f) {
  union { float f; uint32_t u; } c; c.f = f;
  uint32_t u = c.u;
  u += 0x7fffu + ((u >> 16) & 1u);
  return (short)(u >> 16);
}
__device__ __forceinline__ uint32_t pk2bf(float a, float b) {
#if __has_builtin(__builtin_amdgcn_cvt_pk_bf16_f32)
  typedef __attribute__((ext_vector_type(2))) __bf16 bf2;
  union { bf2 v; uint32_t u; } cv;
  cv.v = __builtin_amdgcn_cvt_pk_bf16_f32(a, b);
  return cv.u;
#else
  return (uint32_t)(uint16_t)f2bf(a) | (((uint32_t)(uint16_t)f2bf(b)) << 16);
#endif
}
__device__ __forceinline__ float fexp2(float x) {
#if __has_builtin(__builtin_amdgcn_exp2f)
  return __builtin_amdgcn_exp2f(x);   // raw v_exp_f32, no ocml guard code
#else
  return exp2f(x);
#endif
}
__device__ __forceinline__ bf16x8 mk8(uint32_t a, uint32_t b, uint32_t c, uint32_t d) {
  union { uint32_t u[4]; bf16x8 v; } x;
  x.u[0] = a; x.u[1] = b; x.u[2] = c; x.u[3] = d;
  return x.v;
}
__device__ __forceinline__ void gl_lds16(const short* g, short* l) {
  __builtin_amdgcn_global_load_lds((const __attribute__((address_space(1))) void*)g,
                                   (__attribute__((address_space(3))) void*)l, 16, 0, 0);
}

// ---------------- preprocess ----------------
// blocks [0,512): V -> Vt bf16, transposed to [bh][d][key], keys bit-swapped
// (b2<->b3 per 16-group) to match attn_main's in-register P permutation.
// blocks [512,2560): K fp32->bf16 linear.
__global__ __launch_bounds__(256) void pre_kernel(
    const float* __restrict__ K, const float* __restrict__ V,
    short* __restrict__ Kb, short* __restrict__ Vt) {
  const int t = threadIdx.x;
  if (blockIdx.x >= 512) {
    int i0 = (blockIdx.x - 512) * 256 + t;
#pragma unroll
    for (int r = 0; r < 4; ++r) {
      int i = i0 + r * 524288;
      f32x4 v = ((const f32x4*)K)[i];
      *(uint2*)(Kb + (size_t)i * 4) = make_uint2(pk2bf(v[0], v[1]), pk2bf(v[2], v[3]));
    }
    return;
  }
  __shared__ __align__(16) uint32_t sU[128][64];  // [d][swizzled k2]
  const int vb = blockIdx.x;
  const int bh = vb >> 4;
  const int k0 = (vb & 15) * 128;
  const float* src = V + ((size_t)bh * S_LEN + k0) * D_DIM;
  {
    // phase 1: load key-row pairs coalesced, pack along k, conflict-free b32 writes
    const int a = t & 31;               // d4 = 4a
    const int E = 2 * (a & 15);
    const float* s0 = src + (size_t)(t >> 5) * 2 * D_DIM + a * 4;
#pragma unroll
    for (int p = 0; p < 8; ++p) {
      f32x4 vA = *(const f32x4*)(s0 + p * 16 * D_DIM);
      f32x4 vB = *(const f32x4*)(s0 + p * 16 * D_DIM + D_DIM);
      const int k2 = p * 8 + (t >> 5);  // u32 index = key pair (2k2, 2k2+1)
      const int col = k2 ^ E;
#pragma unroll
      for (int j = 0; j < 4; ++j)
        sU[4 * a + j][col] = pk2bf(vA[j], vB[j]);
    }
  }
  __syncthreads();
  {
    // phase 2: per thread one d-row; 8 x 16B stores; 2 x ds_read_b64 each.
    const int d = t >> 1;
    const int E = 2 * ((t >> 3) & 15);  // 2*((d>>2)&15)
    short* out = Vt + ((size_t)bh * D_DIM + d) * S_LEN + k0 + (t & 1) * 8;
#pragma unroll
    for (int g = 0; g < 8; ++g) {
      const int pb = g * 16 + (t & 1) * 8;
      const int kb1 = ((pb >> 4) << 4) + ((pb & 15) ? 4 : 0);  // bit2<->bit3 swap
      const int k2a = kb1 >> 1;         // even
      const int k2b = k2a + 4;          // kb2 = kb1 + 8
      uint2 lo = *(const uint2*)&sU[d][k2a ^ E];
      uint2 hi = *(const uint2*)&sU[d][k2b ^ E];
      uint4 o; o.x = lo.x; o.y = lo.y; o.z = hi.x; o.w = hi.y;
      *(uint4*)(out + g * 16) = o;
    }
  }
}

// ---------------- main kernel ----------------
// Round-7 structure with PV LAGGED BY ONE CHUNK (T15-style pipeline):
// per chunk G: full barrier (drains K(G), V(G-1) stages) -> issue stages
// K(G+1), V(G) -> read FOREIGN P(G-1) from sP into regs -> light lgkm-only
// barrier (closes read-before-overwrite race on the single sP buffer) ->
// QK(G) -> exp/pack own P into ping-pong regs (pfA/pfB by c parity) ->
// write sP(G) -> PV(G-1) using prev-chunk own pf + pfF regs + V(G-1).
// QK(G) and PV(G-1) are INDEPENDENT -> MFMA pipe fills during softmax VALU
// and QK's dependent chain. Normalize of block j-1 at c==1 (PV of block
// j-1's last chunk lands at c==0). Epilogue runs the deferred PV(31).
// Register discipline: all acc/pf indices compile-time (rule #20); ping-pong
// via c-parity ternaries that fold after #pragma unroll.
__global__ __launch_bounds__(256, 2) void attn_main(
    const short* __restrict__ Kb, const short* __restrict__ Vt,
    const float* __restrict__ Q, float* __restrict__ O) {
  __shared__ __align__(16) short ring[2][16384];  // per slot: K 16KB | V 16KB
  __shared__ __align__(16) short sP[4096];        // 8 regions x 512 (qp,hw,t2)
  __shared__ float sRed[128];                     // [64 q][2 h]
  // total LDS = 65536 + 8192 + 512 = 74240 B -> 2 blocks/CU

  const int t = threadIdx.x;
  const int w = t >> 6;
  const int lane = t & 63;
  const int l31 = lane & 31;
  const int hi = lane >> 5;
  const int h = w & 1;
  const int qp = w >> 1;

  // XCD swizzle: bh = (b&7)*4 + ((b>>3)&3), qtile = b>>5
  const int b = blockIdx.x;
  const int bh = (b & 7) * 4 + ((b >> 3) & 3);
  const int q0 = (b >> 5) * 64;

  const short* Kh = Kb + (size_t)bh * S_LEN * D_DIM;
  const short* Vh = Vt + (size_t)bh * D_DIM * S_LEN;

  // staging constants (K rows: 16 granules, mask 15; V rows: 8 granules, mask 7)
  const int kKey = t >> 4;                       // + r*16
  const int kG   = (t & 15) ^ (kKey & 15);
  const int vD   = t >> 3;                       // + r*32
  const int vG   = (t & 7) ^ (vD & 7);

  auto stageK = [&](int key0, int slot) {
    const short* src = Kh + (size_t)(key0 + kKey) * D_DIM + kG * 8;
    short* dst = &ring[slot][t * 8];
#pragma unroll
    for (int r = 0; r < 4; ++r) gl_lds16(src + r * 16 * D_DIM, dst + r * 2048);
  };
  auto stageV = [&](int key0, int slot) {
    const short* src = Vh + (size_t)vD * S_LEN + key0 + vG * 8;
    short* dst = &ring[slot][8192 + t * 8];
#pragma unroll
    for (int r = 0; r < 4; ++r) gl_lds16(src + (size_t)r * 32 * S_LEN, dst + r * 2048);
  };

  // ---- Q fragments: load fp32, scale, pack (register-resident) ----
  bf16x8 qf[8];
  {
    const float QSCALE = 0.12751743f;  // 128^-0.5 * log2(e)
    const float* Qg = Q + ((size_t)bh * S_LEN + q0 + qp * 32 + l31) * D_DIM;
#pragma unroll
    for (int ks = 0; ks < 8; ++ks) {
      f32x4 a = *(const f32x4*)(Qg + ks * 16 + hi * 8);
      f32x4 c = *(const f32x4*)(Qg + ks * 16 + hi * 8 + 4);
      qf[ks] = mk8(pk2bf(a[0] * QSCALE, a[1] * QSCALE), pk2bf(a[2] * QSCALE, a[3] * QSCALE),
                   pk2bf(c[0] * QSCALE, c[1] * QSCALE), pk2bf(c[2] * QSCALE, c[3] * QSCALE));
    }
  }

  // K A-frag LDS offsets (shorts): row = h*32+l31, logical granule 2ks+hi
  int aK[8];
#pragma unroll
  for (int ks = 0; ks < 8; ++ks)
    aK[ks] = (h * 32 + l31) * 128 + (((2 * ks + hi) ^ (l31 & 15)) << 3);
  // V B-frag LDS offsets: row d = h*64 (+dt*32) + l31, logical granule u*2+hi
  int aV[4];
#pragma unroll
  for (int u = 0; u < 4; ++u)
    aV[u] = (h * 64 + l31) * 64 + (((u * 2 + hi) ^ (l31 & 7)) << 3);

  f32x16 oa[2], oj[2], ojb[2];
#pragma unroll
  for (int d = 0; d < 2; ++d)
#pragma unroll
    for (int r = 0; r < 16; ++r) { oa[d][r] = 0.f; oj[d][r] = 0.f; ojb[d][r] = 0.f; }

  float ssum = 0.f;
  const int spOwn = ((qp * 2 + h) * 2) * 512 + lane * 8;
  const int spFor = ((qp * 2 + (1 - h)) * 2) * 512 + lane * 8;

  // per-wave lv recompute from sRed (h-pair sum; proven rounds 4-6)
  auto loadLv = [&](f32x4* lv) {
#pragma unroll
    for (int g = 0; g < 4; ++g) {
      f32x4 p0 = *(const f32x4*)&sRed[(qp * 32 + g * 8 + 4 * hi) * 2];
      f32x4 p1 = *(const f32x4*)&sRed[(qp * 32 + g * 8 + 4 * hi) * 2 + 4];
      lv[g][0] = __fdividef(1.0f, p0[0] + p0[1]);
      lv[g][1] = __fdividef(1.0f, p0[2] + p0[3]);
      lv[g][2] = __fdividef(1.0f, p1[0] + p1[1]);
      lv[g][3] = __fdividef(1.0f, p1[2] + p1[3]);
    }
  };

  bf16x8 pfA[2], pfB[2];   // ping-pong own-P across chunks (c parity)

  stageK(0, 0);

  for (int j = 0; j < 8; ++j) {
#pragma unroll
    for (int c = 0; c < 4; ++c) {
      const int G = j * 4 + c;
      const int kslot = c & 1;       // == G & 1
      __syncthreads();  // drains vm: K(G) + V(G-1) staged; lgkm: sP(G-1), sRed

      if (G + 1 < 32) stageK((G + 1) * 64, kslot ^ 1);
      stageV(G * 64, kslot);         // V(G) into slot G&1 (V(G-2) dead)

      // read foreign P(G-1) EARLY (single sP buffer; race closed below)
      bf16x8 pfF0, pfF1;
      if (j > 0 || c > 0) {
        pfF0 = *(const bf16x8*)(sP + spFor);
        pfF1 = *(const bf16x8*)(sP + spFor + 512);
      }
      // light barrier: all waves' sP reads complete before any sP(G) write
      asm volatile("s_waitcnt lgkmcnt(0)\n\ts_barrier" ::: "memory");

      if (c == 1 && j > 0) {
        // normalize block j-1 (its last PV landed at c==0): oa += sum*lv
        f32x4 lv[4];
        loadLv(lv);
#pragma unroll
        for (int d = 0; d < 2; ++d)
#pragma unroll
          for (int r = 0; r < 16; ++r) {
            oa[d][r] += (oj[d][r] + ojb[d][r]) * lv[r >> 2][r & 3];
            oj[d][r] = 0.f;
            ojb[d][r] = 0.f;
          }
      }

      // ---- QK^T(G): one 32x32 tile, TWO independent MFMA chains ----
      const short* pK = &ring[kslot][0];
      f32x16 sc0, sc1;
#pragma unroll
      for (int r = 0; r < 16; ++r) { sc0[r] = 0.f; sc1[r] = 0.f; }
#pragma unroll
      for (int ks = 0; ks < 4; ++ks) {
        bf16x8 a0 = *(const bf16x8*)(pK + aK[2 * ks]);
        bf16x8 a1 = *(const bf16x8*)(pK + aK[2 * ks + 1]);
        sc0 = __builtin_amdgcn_mfma_f32_32x32x16_bf16(a0, qf[2 * ks], sc0, 0, 0, 0);
        sc1 = __builtin_amdgcn_mfma_f32_32x32x16_bf16(a1, qf[2 * ks + 1], sc1, 0, 0, 0);
      }
#pragma unroll
      for (int r = 0; r < 16; ++r) sc0[r] = fexp2(sc0[r] + sc1[r]);

      // pack own P(G) into ping-pong regs (c parity folds) + write sP(G)
      {
        bf16x8 c0 = mk8(pk2bf(sc0[0], sc0[1]), pk2bf(sc0[2], sc0[3]),
                        pk2bf(sc0[4], sc0[5]), pk2bf(sc0[6], sc0[7]));
        bf16x8 c1 = mk8(pk2bf(sc0[8], sc0[9]), pk2bf(sc0[10], sc0[11]),
                        pk2bf(sc0[12], sc0[13]), pk2bf(sc0[14], sc0[15]));
        if ((c & 1) == 0) { pfA[0] = c0; pfA[1] = c1; }
        else             { pfB[0] = c0; pfB[1] = c1; }
        *(bf16x8*)(sP + spOwn) = c0;
        *(bf16x8*)(sP + spOwn + 512) = c1;
      }
      {  // tree-sum (depth 4)
        float a0 = sc0[0] + sc0[1], a1 = sc0[2] + sc0[3], a2 = sc0[4] + sc0[5], a3 = sc0[6] + sc0[7];
        float a4 = sc0[8] + sc0[9], a5 = sc0[10] + sc0[11], a6 = sc0[12] + sc0[13], a7 = sc0[14] + sc0[15];
        float b0 = a0 + a1, b1 = a2 + a3, b2 = a4 + a5, b3 = a6 + a7;
        ssum += (b0 + b1) + (b2 + b3);
      }
      if (c == 3) {
        ssum += __shfl_xor(ssum, 32);
        if (lane < 32) sRed[(qp * 32 + l31) * 2 + h] = ssum;
        ssum = 0.f;
      }

      // ---- PV(G-1): prev own pf + pfF regs + V(G-1) from slot kslot^1 ----
      if (j > 0 || c > 0) {
        const short* pV = &ring[kslot ^ 1][8192];
#pragma unroll
        for (int hw = 0; hw < 2; ++hw)
#pragma unroll
          for (int t2 = 0; t2 < 2; ++t2) {
            bf16x8 pp = ((c & 1) == 0) ? pfB[t2] : pfA[t2];  // prev chunk own
            bf16x8 a = (hw == h) ? pp : (t2 == 0 ? pfF0 : pfF1);
#pragma unroll
            for (int dt = 0; dt < 2; ++dt) {
              bf16x8 bv = *(const bf16x8*)(pV + aV[hw * 2 + t2] + dt * 2048);
              if (hw == 0)
                oj[dt] = __builtin_amdgcn_mfma_f32_32x32x16_bf16(a, bv, oj[dt], 0, 0, 0);
              else
                ojb[dt] = __builtin_amdgcn_mfma_f32_32x32x16_bf16(a, bv, ojb[dt], 0, 0, 0);
            }
          }
      }
    }
  }

  __syncthreads();  // drains V(31) stage; sP(31) + sRed(31) visible
  // ---- epilogue: deferred PV(31), then final normalize + store ----
  {
    bf16x8 pfF0 = *(const bf16x8*)(sP + spFor);
    bf16x8 pfF1 = *(const bf16x8*)(sP + spFor + 512);
    const short* pV = &ring[1][8192];   // V(31) in slot 1
#pragma unroll
    for (int hw = 0; hw < 2; ++hw)
#pragma unroll
      for (int t2 = 0; t2 < 2; ++t2) {
        bf16x8 a = (hw == h) ? pfB[t2] : (t2 == 0 ? pfF0 : pfF1);  // c=3 wrote pfB
#pragma unroll
        for (int dt = 0; dt < 2; ++dt) {
          bf16x8 bv = *(const bf16x8*)(pV + aV[hw * 2 + t2] + dt * 2048);
          if (hw == 0)
            oj[dt] = __builtin_amdgcn_mfma_f32_32x32x16_bf16(a, bv, oj[dt], 0, 0, 0);
          else
            ojb[dt] = __builtin_amdgcn_mfma_f32_32x32x16_bf16(a, bv, ojb[dt], 0, 0, 0);
        }
      }
  }
  {
    f32x4 lv[4];
    loadLv(lv);
    float* Og = O + ((size_t)bh * S_LEN + q0) * D_DIM;
#pragma unroll
    for (int d = 0; d < 2; ++d)
#pragma unroll
      for (int r = 0; r < 16; ++r) {
        float val = oa[d][r] + (oj[d][r] + ojb[d][r]) * lv[r >> 2][r & 3];
        int row = qp * 32 + (r & 3) + 8 * (r >> 2) + 4 * hi;
        int col = h * 64 + d * 32 + l31;
        Og[row * D_DIM + col] = val;
      }
  }
}

extern "C" void kernel_launch(void* const* d_in, const int* in_sizes, int n_in,
                              void* d_out, int out_size, void* d_ws, size_t ws_size,
                              hipStream_t stream) {
  const float* Q = (const float*)d_in[0];
  const float* K = (const float*)d_in[1];
  const float* V = (const float*)d_in[2];
  float* Out = (float*)d_out;
  const size_t tElems = (size_t)32 * S_LEN * D_DIM;

  short* Kb  = (short*)d_ws;
  short* Vtb = Kb + tElems;

  pre_kernel<<<2560, 256, 0, stream>>>(K, V, Kb, Vtb);
  attn_main<<<1024, 256, 0, stream>>>(Kb, Vtb, Q, Out);
}